// Round 1
// baseline (483.354 us; speedup 1.0000x reference)
//
#include <hip/hip_runtime.h>

// MapDensePoseTex: per-pixel part/uv -> lut -> gather from tex, 16 channels.
// Shapes fixed by setup_inputs(): tex (8,16,512,512) f32, iuv (8,3,512,512) i32,
// lut (24,256,256,2) f32, tex_res = 512 (read on device from d_in[3]).
// Output (8,16,512,512) f32.

#define N_PARTS 24

__global__ __launch_bounds__(256) void MapDensePoseTexModule_22101901705512_kernel(
    const float* __restrict__ tex,
    const int*   __restrict__ iuv,
    const float* __restrict__ lut,
    const int*   __restrict__ texres,
    float*       __restrict__ out)
{
    constexpr int B = 8, C = 16, H = 512, W = 512;
    const int   R     = texres[0];          // 512
    const float scale = (float)(R - 1);     // 511.0f

    // Each thread handles 4 consecutive w pixels -> int4 iuv loads, float4 stores.
    const int t  = blockIdx.x * blockDim.x + threadIdx.x;
    const int WP = W / 4;                   // 128 pixel-groups per row
    const int w4  = (t % WP) * 4;
    const int tmp = t / WP;
    const int h   = tmp % H;
    const int b   = tmp / H;
    if (b >= B) return;

    const size_t hw    = (size_t)H * W;
    const size_t ibase = (size_t)b * 3 * hw + (size_t)h * W + w4;
    const int4 p4 = *(const int4*)(iuv + ibase);            // part plane
    const int4 u4 = *(const int4*)(iuv + ibase + hw);       // u plane
    const int4 v4 = *(const int4*)(iuv + ibase + 2 * hw);   // v plane

    const int parts[4] = {p4.x, p4.y, p4.z, p4.w};
    const int us[4]    = {u4.x, u4.y, u4.z, u4.w};
    const int vs[4]    = {v4.x, v4.y, v4.z, v4.w};

    int  off[4];
    bool m[4];

    #pragma unroll
    for (int j = 0; j < 4; ++j) {
        m[j] = parts[j] > 0;
        int i = parts[j] - 1;
        i = i < 0 ? 0 : (i > N_PARTS - 1 ? N_PARTS - 1 : i);
        // Faithful to reference: f32 divide, clip, *255, round-half-even.
        const float fu = fminf(fmaxf((float)us[j] / 255.0f, 0.0f), 1.0f);
        const float fv = fminf(fmaxf((float)vs[j] / 255.0f, 0.0f), 1.0f);
        const int ui = (int)rintf(fu * 255.0f);
        const int vi = (int)rintf(fv * 255.0f);
        const float2 s = *(const float2*)(lut + (((size_t)i * 256 + vi) * 256 + ui) * 2);
        const int uI = (int)rintf(s.x * scale);
        const int vI = (int)rintf((1.0f - s.y) * scale);
        off[j] = vI * R + uI;               // always in-range, even when masked
    }

    const size_t plane = (size_t)R * R;
    const float* texb  = tex + (size_t)b * C * plane;
    float*       outb  = out + ((size_t)b * C * H + h) * W + w4;

    #pragma unroll
    for (int c = 0; c < C; ++c) {
        const float* tc = texb + (size_t)c * plane;
        float4 o;
        o.x = m[0] ? tc[off[0]] : 0.0f;
        o.y = m[1] ? tc[off[1]] : 0.0f;
        o.z = m[2] ? tc[off[2]] : 0.0f;
        o.w = m[3] ? tc[off[3]] : 0.0f;
        *(float4*)(outb + (size_t)c * hw) = o;
    }
}

extern "C" void kernel_launch(void* const* d_in, const int* in_sizes, int n_in,
                              void* d_out, int out_size, void* d_ws, size_t ws_size,
                              hipStream_t stream) {
    const float* tex    = (const float*)d_in[0];
    const int*   iuv    = (const int*)d_in[1];
    const float* lut    = (const float*)d_in[2];
    const int*   texres = (const int*)d_in[3];
    float*       out    = (float*)d_out;

    // B*H*(W/4) = 8*512*128 = 524288 threads -> 2048 blocks of 256.
    const int threads = 8 * 512 * (512 / 4);
    dim3 block(256);
    dim3 grid((threads + 255) / 256);
    MapDensePoseTexModule_22101901705512_kernel<<<grid, block, 0, stream>>>(
        tex, iuv, lut, texres, out);
}

// Round 2
// 403.148 us; speedup vs baseline: 1.1989x; 1.1989x over previous
//
#include <hip/hip_runtime.h>

// MapDensePoseTex, two-pass plane-blocked version.
// Shapes from setup_inputs(): tex (8,16,512,512) f32, iuv (8,3,512,512) i32,
// lut (24,256,256,2) f32, tex_res = 512. Output (8,16,512,512) f32.
//
// Pass 1: per-pixel offset = vI*R+uI (or -1 if masked) -> d_ws (B*H*W int32).
// Pass 2: one block gathers 1024 pixels of ONE (b,c) plane; block-id swizzle
// pins each plane's blocks to one XCD (assuming blockIdx%8 -> XCD round-robin)
// so the 1 MB plane stays L2-resident and is fetched ~once.

#define N_PARTS 24

__global__ __launch_bounds__(256) void dp_offsets_kernel(
    const int*   __restrict__ iuv,
    const float* __restrict__ lut,
    int*         __restrict__ offs,
    int R)
{
    constexpr int H = 512, W = 512;
    const float scale = (float)(R - 1);

    const int t = blockIdx.x * blockDim.x + threadIdx.x;   // one thread = 4 px
    const size_t hw = (size_t)H * W;
    const int pix4 = t * 4;                 // flat pixel index within batch*HW
    const int b = pix4 >> 18;               // /(H*W) with H*W=262144
    const int p = pix4 & (int)(hw - 1);

    const size_t ibase = (size_t)b * 3 * hw + p;
    const int4 p4 = *(const int4*)(iuv + ibase);
    const int4 u4 = *(const int4*)(iuv + ibase + hw);
    const int4 v4 = *(const int4*)(iuv + ibase + 2 * hw);

    const int parts[4] = {p4.x, p4.y, p4.z, p4.w};
    const int us[4]    = {u4.x, u4.y, u4.z, u4.w};
    const int vs[4]    = {v4.x, v4.y, v4.z, v4.w};

    int4 o4;
    int* o = &o4.x;
    #pragma unroll
    for (int j = 0; j < 4; ++j) {
        int i = parts[j] - 1;
        i = i < 0 ? 0 : (i > N_PARTS - 1 ? N_PARTS - 1 : i);
        // Faithful to reference: f32 divide, clip, *255, round-half-even.
        const float fu = fminf(fmaxf((float)us[j] / 255.0f, 0.0f), 1.0f);
        const float fv = fminf(fmaxf((float)vs[j] / 255.0f, 0.0f), 1.0f);
        const int ui = (int)rintf(fu * 255.0f);
        const int vi = (int)rintf(fv * 255.0f);
        const float2 s = *(const float2*)(lut + (((size_t)i * 256 + vi) * 256 + ui) * 2);
        const int uI = (int)rintf(s.x * scale);
        const int vI = (int)rintf((1.0f - s.y) * scale);
        o[j] = (parts[j] > 0) ? (vI * R + uI) : -1;
    }
    *(int4*)(offs + (size_t)b * hw + p) = o4;
}

// planesPerXcd = B*C/8 = 16, blocksPerPlane = H*W/1024 = 256.
__global__ __launch_bounds__(256) void dp_gather_kernel(
    const float* __restrict__ tex,
    const int*   __restrict__ offs,
    float*       __restrict__ out,
    int R)
{
    constexpr int C = 16, H = 512, W = 512;
    const size_t hw    = (size_t)H * W;
    const size_t plane = (size_t)R * R;

    const int bid  = blockIdx.x;
    const int xcd  = bid & 7;                // assumed XCD round-robin
    const int slot = bid >> 3;               // 0..4095 per xcd
    const int pl_local = slot >> 8;          // 0..15
    const int inner    = slot & 255;         // 0..255 block within plane
    const int pidx = xcd * 16 + pl_local;    // global plane 0..127
    const int b = pidx >> 4;                 // batch  (each XCD = one batch)
    const int c = pidx & 15;

    const int px = inner * 1024 + threadIdx.x * 4;   // 4 pixels per thread

    const int4 o4 = *(const int4*)(offs + (size_t)b * hw + px);
    const float* tc = tex + ((size_t)b * C + c) * plane;

    float4 r;
    r.x = (o4.x >= 0) ? tc[o4.x] : 0.0f;
    r.y = (o4.y >= 0) ? tc[o4.y] : 0.0f;
    r.z = (o4.z >= 0) ? tc[o4.z] : 0.0f;
    r.w = (o4.w >= 0) ? tc[o4.w] : 0.0f;

    *(float4*)(out + ((size_t)b * C + c) * hw + px) = r;
}

// ---- fallback single-pass kernel (used only if ws_size is too small) ----
__global__ __launch_bounds__(256) void dp_fused_kernel(
    const float* __restrict__ tex,
    const int*   __restrict__ iuv,
    const float* __restrict__ lut,
    float*       __restrict__ out,
    int R)
{
    constexpr int B = 8, C = 16, H = 512, W = 512;
    const float scale = (float)(R - 1);
    const int t  = blockIdx.x * blockDim.x + threadIdx.x;
    const int WP = W / 4;
    const int w4  = (t % WP) * 4;
    const int tmp = t / WP;
    const int h   = tmp % H;
    const int b   = tmp / H;
    if (b >= B) return;

    const size_t hw    = (size_t)H * W;
    const size_t ibase = (size_t)b * 3 * hw + (size_t)h * W + w4;
    const int4 p4 = *(const int4*)(iuv + ibase);
    const int4 u4 = *(const int4*)(iuv + ibase + hw);
    const int4 v4 = *(const int4*)(iuv + ibase + 2 * hw);

    const int parts[4] = {p4.x, p4.y, p4.z, p4.w};
    const int us[4]    = {u4.x, u4.y, u4.z, u4.w};
    const int vs[4]    = {v4.x, v4.y, v4.z, v4.w};

    int  off[4]; bool m[4];
    #pragma unroll
    for (int j = 0; j < 4; ++j) {
        m[j] = parts[j] > 0;
        int i = parts[j] - 1;
        i = i < 0 ? 0 : (i > N_PARTS - 1 ? N_PARTS - 1 : i);
        const float fu = fminf(fmaxf((float)us[j] / 255.0f, 0.0f), 1.0f);
        const float fv = fminf(fmaxf((float)vs[j] / 255.0f, 0.0f), 1.0f);
        const int ui = (int)rintf(fu * 255.0f);
        const int vi = (int)rintf(fv * 255.0f);
        const float2 s = *(const float2*)(lut + (((size_t)i * 256 + vi) * 256 + ui) * 2);
        off[j] = ((int)rintf((1.0f - s.y) * scale)) * R + (int)rintf(s.x * scale);
    }

    const size_t plane = (size_t)R * R;
    const float* texb  = tex + (size_t)b * C * plane;
    float*       outb  = out + ((size_t)b * C * H + h) * W + w4;

    #pragma unroll
    for (int c = 0; c < C; ++c) {
        const float* tc = texb + (size_t)c * plane;
        float4 o;
        o.x = m[0] ? tc[off[0]] : 0.0f;
        o.y = m[1] ? tc[off[1]] : 0.0f;
        o.z = m[2] ? tc[off[2]] : 0.0f;
        o.w = m[3] ? tc[off[3]] : 0.0f;
        *(float4*)(outb + (size_t)c * hw) = o;
    }
}

extern "C" void kernel_launch(void* const* d_in, const int* in_sizes, int n_in,
                              void* d_out, int out_size, void* d_ws, size_t ws_size,
                              hipStream_t stream) {
    const float* tex = (const float*)d_in[0];
    const int*   iuv = (const int*)d_in[1];
    const float* lut = (const float*)d_in[2];
    float*       out = (float*)d_out;

    constexpr int B = 8, C = 16, H = 512, W = 512;
    // Derive R from tex element count: B*C*R*R.
    int R = 512;
    {
        long long pe = (long long)in_sizes[0] / (B * C);
        int r = 1; while ((long long)(r + 1) * (r + 1) <= pe) ++r;
        R = r;
    }

    const size_t offs_bytes = (size_t)B * H * W * sizeof(int);   // 8 MB
    if (ws_size >= offs_bytes) {
        int* offs = (int*)d_ws;
        // Pass 1: 8*512*512/4 threads = 2048 blocks.
        dp_offsets_kernel<<<dim3((B * H * W / 4 + 255) / 256), dim3(256), 0, stream>>>(
            iuv, lut, offs, R);
        // Pass 2: B*C planes * (H*W/1024) blocks = 128*256 = 32768 blocks.
        dp_gather_kernel<<<dim3(B * C * (H * W / 1024)), dim3(256), 0, stream>>>(
            tex, offs, out, R);
    } else {
        const int threads = B * H * (W / 4);
        dp_fused_kernel<<<dim3((threads + 255) / 256), dim3(256), 0, stream>>>(
            tex, iuv, lut, out, R);
    }
}